// Round 6
// baseline (133.107 us; speedup 1.0000x reference)
//
#include <hip/hip_runtime.h>
#include <math.h>

#define EPS      0.1f
#define INV_EPS  10.0f
#define THRESH   0.1f
#define MAX_IT   20

// Problem sizes (fixed by reference setup_inputs)
#define BB 4
#define NN 1024
#define MM 1024
#define DD 512

#define MU_P (1.0f / 1024.0f + 1e-8f)

// Sinkhorn loop config: 256 blocks x 512 threads, 16 rows/block, 2 rows/wave
#define GBLK 256
#define TBLK 512

// workspace layout (float offsets)
#define OFF_K    ((size_t)0)                   // K = exp(-C/eps) [B,N,M] bf16 (8.4 MB)
#define OFF_NX   ((size_t)2097152)             // |x_i| [B*N]
#define OFF_NY   (OFF_NX + 4096)               // |y_j| [B*M]
#define OFF_NUP  (OFF_NY + 4096)               // nu + 1e-8 [B*M]
#define OFF_CS   (OFF_NUP + 4096)              // colsum rotation [3][4096]
#define OFF_FLG  (OFF_CS + 12288)              // barrier flags [2][256] ulong

#define LDA 40   // padded ushort row stride (80 B = 20-bank rotation, <=2-way alias)

typedef __bf16 bf16x8 __attribute__((ext_vector_type(8)));
typedef float f32x4 __attribute__((ext_vector_type(4)));
typedef unsigned long long u64;

__device__ __forceinline__ float wave_reduce_sum(float x) {
#pragma unroll
  for (int off = 32; off > 0; off >>= 1) x += __shfl_xor(x, off, 64);
  return x;
}

// -------- norms of x/y rows + init of sinkhorn state (merged) --------
__global__ void __launch_bounds__(256) norms_kernel(const float* __restrict__ x,
                                                    const float* __restrict__ y,
                                                    float* __restrict__ nx,
                                                    float* __restrict__ ny,
                                                    const float* __restrict__ nu,
                                                    float* nup, float* colsum,
                                                    int* flagsi, float* out) {
  const int tid = threadIdx.x;
  int gt = blockIdx.x * 256 + tid;
  if (gt < BB * MM) {
    nup[gt] = nu[gt] + 1e-8f;
    colsum[4096 + gt] = 0.f;      // colsum[1] is iteration 0's add target
  }
  if (gt < 1024) flagsi[gt] = 0;  // 2 x 256 ulong flag slots
  if (gt < BB) out[gt] = 0.f;

  const int w = tid >> 6, lane = tid & 63;
  const int r = blockIdx.x * 4 + w;                 // 0..8191
  const float* src = (r < BB * NN) ? (x + (size_t)r * DD)
                                   : (y + (size_t)(r - BB * NN) * DD);
  const float4* s4 = (const float4*)src;
  float4 a = s4[lane];
  float4 b = s4[lane + 64];
  float ss = a.x * a.x + a.y * a.y + a.z * a.z + a.w * a.w +
             b.x * b.x + b.y * b.y + b.z * b.z + b.w * b.w;
  ss = wave_reduce_sum(ss);
  if (lane == 0) {
    float n = sqrtf(ss);
    if (r < BB * NN) nx[r] = n; else ny[r - BB * NN] = n;
  }
}

// pack two floats to bf16x2 (RNE via compiler cast)
__device__ __forceinline__ uint pk2(float a, float b) {
  __bf16 ha = (__bf16)a, hb = (__bf16)b;
  return (uint)*(ushort*)&ha | ((uint)*(ushort*)&hb << 16);
}

// -------- MFMA single-pass bf16 GEMM: dot = X Y^T,
// epilogue K = exp(-(1 - dot/denom)/eps) stored bf16 (row-major). --------
__global__ void __launch_bounds__(256) gemm_kernel(const float* __restrict__ x,
                                                   const float* __restrict__ y,
                                                   const float* __restrict__ nxg,
                                                   const float* __restrict__ nyg,
                                                   ushort* __restrict__ K) {
  __shared__ ushort Ah[64 * LDA];      // 5 KB, padded
  __shared__ ushort Bh[128 * LDA];     // 10 KB, padded
  __shared__ float s_nx[64], s_ny[128];

  const int b = blockIdx.z;
  const int i0 = blockIdx.y * 64;    // m-tile
  const int j0 = blockIdx.x * 128;   // n-tile
  const int t = threadIdx.x;
  const int w = t >> 6, lane = t & 63;
  const int m16 = lane & 15, q = lane >> 4;
  const int wm = (w & 1) * 32, wn = (w >> 1) * 64;

  const int srow = t >> 3;            // 0..31 staging row within pass
  const int skq = (t & 7) * 4;        // staging k-offset (elements)

  const float* xb = x + ((size_t)b * NN + i0 + srow) * DD + skq;
  const float* yb = y + ((size_t)b * MM + j0 + srow) * DD + skq;

  f32x4 acc[2][4];
#pragma unroll
  for (int mi = 0; mi < 2; ++mi)
#pragma unroll
    for (int ni = 0; ni < 4; ++ni) acc[mi][ni] = (f32x4)0.f;

  for (int k0 = 0; k0 < DD; k0 += 32) {
    float4 ax[2], by[4];
#pragma unroll
    for (int p = 0; p < 2; ++p) ax[p] = *(const float4*)(xb + (size_t)p * 32 * DD + k0);
#pragma unroll
    for (int p = 0; p < 4; ++p) by[p] = *(const float4*)(yb + (size_t)p * 32 * DD + k0);
    __syncthreads();
#pragma unroll
    for (int p = 0; p < 2; ++p)
      *(uint2*)&Ah[(srow + p * 32) * LDA + skq] =
          make_uint2(pk2(ax[p].x, ax[p].y), pk2(ax[p].z, ax[p].w));
#pragma unroll
    for (int p = 0; p < 4; ++p)
      *(uint2*)&Bh[(srow + p * 32) * LDA + skq] =
          make_uint2(pk2(by[p].x, by[p].y), pk2(by[p].z, by[p].w));
    __syncthreads();

    bf16x8 ahf[2], bhf[4];
#pragma unroll
    for (int mi = 0; mi < 2; ++mi)
      ahf[mi] = *(const bf16x8*)&Ah[(wm + mi * 16 + m16) * LDA + q * 8];
#pragma unroll
    for (int ni = 0; ni < 4; ++ni)
      bhf[ni] = *(const bf16x8*)&Bh[(wn + ni * 16 + m16) * LDA + q * 8];
#pragma unroll
    for (int mi = 0; mi < 2; ++mi)
#pragma unroll
      for (int ni = 0; ni < 4; ++ni)
        acc[mi][ni] = __builtin_amdgcn_mfma_f32_16x16x32_bf16(ahf[mi], bhf[ni], acc[mi][ni], 0, 0, 0);
  }

  // epilogue: K = exp(-(1 - dot/den)/eps), bf16
  if (t < 64) s_nx[t] = nxg[b * NN + i0 + t];
  else if (t < 192) s_ny[t - 64] = nyg[b * MM + j0 + t - 64];
  __syncthreads();

#pragma unroll
  for (int mi = 0; mi < 2; ++mi)
#pragma unroll
    for (int ni = 0; ni < 4; ++ni)
#pragma unroll
      for (int r = 0; r < 4; ++r) {
        const int m = wm + mi * 16 + q * 4 + r;
        const int n = wn + ni * 16 + m16;
        float den = fmaxf(s_nx[m] * s_ny[n], 1e-8f);
        float cv = 1.0f - acc[mi][ni][r] / den;
        float kf = __expf(-cv * INV_EPS);
        __bf16 hb = (__bf16)kf;
        K[((size_t)b * NN + i0 + m) * MM + j0 + n] = *(ushort*)&hb;
      }
}

__device__ __forceinline__ void unpack8(uint4 k, float* kf) {
  kf[0] = __uint_as_float(k.x << 16);
  kf[1] = __uint_as_float(k.x & 0xffff0000u);
  kf[2] = __uint_as_float(k.y << 16);
  kf[3] = __uint_as_float(k.y & 0xffff0000u);
  kf[4] = __uint_as_float(k.z << 16);
  kf[5] = __uint_as_float(k.z & 0xffff0000u);
  kf[6] = __uint_as_float(k.w << 16);
  kf[7] = __uint_as_float(k.w & 0xffff0000u);
}

// -------- persistent Sinkhorn, ONE barrier per iteration, 256 blocks --------
// rowsum_i = sum_j K_ij wv_j ; u_i = eps(log mu' - log rowsum_i); wu_i = mu'/rowsum_i
// colsum_j = sum_i K_ij wu_i (atomic-accumulated grid-wide, 3-buffer rotation)
// wv_j = nu'_j / colsum_j (recomputed LOCALLY by every block -> no v-barrier)
// barrier: all-to-all, one ulong {gen, err} per block, depth-2 ping-pong slots.
__global__ void __launch_bounds__(TBLK) sinkhorn_kernel(
    const ushort* __restrict__ K, float* __restrict__ colsum,
    const float* __restrict__ nup, u64* __restrict__ flags,
    float* __restrict__ out) {
  const int tid = threadIdx.x;
  const int bid = blockIdx.x;
  const int lane = tid & 63;
  const int w = tid >> 6;                 // 0..7
  const int b = bid >> 6;                 // batch (64 blocks per batch)
  const int rbase = (bid & 63) * 16;      // first owned row within batch

  __shared__ float swv[1024];
  __shared__ float spart[8][1024];        // 32 KB per-wave column partials
  __shared__ float s_red;
  __shared__ int s_conv;

  const float eps_log_mu = EPS * __logf(MU_P);
  float u_prev[2] = {0.f, 0.f};
  float wu_reg[2] = {0.f, 0.f};
  int T = 0;

  for (int it = 0; it < MAX_IT; ++it) {
    const int genv = it + 1;
    // ---- stage wv (local v reconstruction; it=0: v=0 -> wv=1) ----
    if (tid == 0) s_red = 0.f;
    if (it == 0) {
      swv[tid] = 1.f;
      swv[tid + 512] = 1.f;
    } else {
      const float* cs = colsum + (it % 3) * 4096 + b * MM;
      float c0 = __hip_atomic_load(cs + tid, __ATOMIC_RELAXED, __HIP_MEMORY_SCOPE_AGENT);
      float c1 = __hip_atomic_load(cs + tid + 512, __ATOMIC_RELAXED, __HIP_MEMORY_SCOPE_AGENT);
      swv[tid] = nup[b * MM + tid] / c0;
      swv[tid + 512] = nup[b * MM + tid + 512] / c1;
    }
    __syncthreads();

    float wvr[16];
    {
      const float4* wp = (const float4*)swv;
      *(float4*)&wvr[0] = wp[lane * 2];
      *(float4*)&wvr[4] = wp[lane * 2 + 1];
      *(float4*)&wvr[8] = wp[128 + lane * 2];
      *(float4*)&wvr[12] = wp[129 + lane * 2];
    }
    float creg[16];
#pragma unroll
    for (int t2 = 0; t2 < 16; ++t2) creg[t2] = 0.f;

    // preload this wave's 2 K-rows (L2-resident)
    uint4 kq[2][2];
#pragma unroll
    for (int rr = 0; rr < 2; ++rr) {
      const uint4* kp = (const uint4*)(K + ((size_t)b * NN + rbase + w * 2 + rr) * MM);
      kq[rr][0] = kp[lane];
      kq[rr][1] = kp[lane + 64];
    }

    float werr = 0.f;
#pragma unroll
    for (int rr = 0; rr < 2; ++rr) {
      float kf[16];
      unpack8(kq[rr][0], kf);
      unpack8(kq[rr][1], kf + 8);
      float s = 0.f;
#pragma unroll
      for (int t2 = 0; t2 < 16; ++t2) s = fmaf(kf[t2], wvr[t2], s);
      s = wave_reduce_sum(s);
      float unv = eps_log_mu - EPS * __logf(s);
      werr += fabsf(unv - u_prev[rr]);
      u_prev[rr] = unv;
      float wu = MU_P / s;          // exp(u_new/eps), exactly
      wu_reg[rr] = wu;
#pragma unroll
      for (int t2 = 0; t2 < 16; ++t2) creg[t2] = fmaf(wu, kf[t2], creg[t2]);
    }
    if (lane == 0) atomicAdd(&s_red, werr);

    // publish per-wave column partials to LDS
    {
      float* pr = &spart[w][0];
      *(float4*)&pr[lane * 8] = *(float4*)&creg[0];
      *(float4*)&pr[lane * 8 + 4] = *(float4*)&creg[4];
      *(float4*)&pr[512 + lane * 8] = *(float4*)&creg[8];
      *(float4*)&pr[512 + lane * 8 + 4] = *(float4*)&creg[12];
    }
    __syncthreads();

    // cross-wave reduce + atomic add into next colsum; zero rotation buffer
    {
      float* csn = colsum + ((it + 1) % 3) * 4096 + b * MM;
      const int j0 = tid * 2;
      float s0 = 0.f, s1 = 0.f;
#pragma unroll
      for (int ww = 0; ww < 8; ++ww) {
        float2 p = *(const float2*)&spart[ww][j0];
        s0 += p.x;
        s1 += p.y;
      }
      unsafeAtomicAdd(&csn[j0], s0);
      unsafeAtomicAdd(&csn[j0 + 1], s1);
      if (tid < 16) {
        float* csz = colsum + ((it + 2) % 3) * 4096;
        __hip_atomic_store(&csz[bid * 16 + tid], 0.f, __ATOMIC_RELAXED, __HIP_MEMORY_SCOPE_AGENT);
      }
    }

    // ---- all-to-all barrier: publish {gen, err}, poll, local conv decision ----
    asm volatile("s_waitcnt vmcnt(0)" ::: "memory");
    __syncthreads();
    if (tid == 0) {
      u64 f = ((u64)(uint)genv << 32) | (u64)__float_as_uint(s_red);
      __hip_atomic_store(&flags[(genv & 1) * GBLK + bid], f, __ATOMIC_RELAXED, __HIP_MEMORY_SCOPE_AGENT);
    }
    if (tid < 64) {
      const u64* fl = flags + (genv & 1) * GBLK;
      u64 f0, f1, f2, f3;
      for (;;) {
        f0 = __hip_atomic_load(fl + tid, __ATOMIC_RELAXED, __HIP_MEMORY_SCOPE_AGENT);
        f1 = __hip_atomic_load(fl + tid + 64, __ATOMIC_RELAXED, __HIP_MEMORY_SCOPE_AGENT);
        f2 = __hip_atomic_load(fl + tid + 128, __ATOMIC_RELAXED, __HIP_MEMORY_SCOPE_AGENT);
        f3 = __hip_atomic_load(fl + tid + 192, __ATOMIC_RELAXED, __HIP_MEMORY_SCOPE_AGENT);
        if (__all(((f0 >> 32) >= (u64)genv) && ((f1 >> 32) >= (u64)genv) &&
                  ((f2 >> 32) >= (u64)genv) && ((f3 >> 32) >= (u64)genv))) break;
        __builtin_amdgcn_s_sleep(1);
      }
      float e = __uint_as_float((uint)f0) + __uint_as_float((uint)f1) +
                __uint_as_float((uint)f2) + __uint_as_float((uint)f3);
      e = wave_reduce_sum(e);
      if (tid == 0) s_conv = (e * (1.0f / (float)BB) < THRESH) ? 1 : 0;
    }
    __syncthreads();
    T = it;
    if (s_conv) break;
  }

  // ---- final: reconstruct converged wv locally, accumulate transport cost ----
  {
    const float* cs = colsum + ((T + 1) % 3) * 4096 + b * MM;
    float c0 = __hip_atomic_load(cs + tid, __ATOMIC_RELAXED, __HIP_MEMORY_SCOPE_AGENT);
    float c1 = __hip_atomic_load(cs + tid + 512, __ATOMIC_RELAXED, __HIP_MEMORY_SCOPE_AGENT);
    swv[tid] = nup[b * MM + tid] / c0;
    swv[tid + 512] = nup[b * MM + tid + 512] / c1;
  }
  if (tid == 0) s_red = 0.f;
  __syncthreads();

  float wvr[16];
  {
    const float4* wp = (const float4*)swv;
    *(float4*)&wvr[0] = wp[lane * 2];
    *(float4*)&wvr[4] = wp[lane * 2 + 1];
    *(float4*)&wvr[8] = wp[128 + lane * 2];
    *(float4*)&wvr[12] = wp[129 + lane * 2];
  }

  float wcost = 0.f;
#pragma unroll
  for (int rr = 0; rr < 2; ++rr) {
    const int r = rbase + w * 2 + rr;
    const uint4* kp = (const uint4*)(K + ((size_t)b * NN + r) * MM);
    uint4 k0 = kp[lane], k1 = kp[lane + 64];
    float kf[16];
    unpack8(k0, kf);
    unpack8(k1, kf + 8);
    float s = 0.f;
#pragma unroll
    for (int t2 = 0; t2 < 16; ++t2)
      s = fmaf(kf[t2] * wvr[t2], -EPS * __logf(kf[t2]), s);   // pi * C, C = -eps log K
    s = wave_reduce_sum(s) * wu_reg[rr];
    if (lane == 0) wcost += s;
  }
  if (lane == 0) atomicAdd(&s_red, wcost);
  __syncthreads();
  if (tid == 0) atomicAdd(out + b, s_red);
}

extern "C" void kernel_launch(void* const* d_in, const int* in_sizes, int n_in,
                              void* d_out, int out_size, void* d_ws, size_t ws_size,
                              hipStream_t stream) {
  const float* x = (const float*)d_in[0];
  const float* y = (const float*)d_in[1];
  const float* nu = (const float*)d_in[2];
  float* out = (float*)d_out;
  float* ws = (float*)d_ws;

  ushort* K = (ushort*)(ws + OFF_K);
  float* nx = ws + OFF_NX;
  float* ny = ws + OFF_NY;
  float* nup = ws + OFF_NUP;
  float* cs = ws + OFF_CS;
  u64* flg = (u64*)(ws + OFF_FLG);

  norms_kernel<<<2048, 256, 0, stream>>>(x, y, nx, ny, nu, nup, cs, (int*)flg, out);
  gemm_kernel<<<dim3(8, 16, 4), 256, 0, stream>>>(x, y, nx, ny, K);

  void* args[] = {(void*)&K, (void*)&cs, (void*)&nup, (void*)&flg, (void*)&out};
  hipLaunchCooperativeKernel(reinterpret_cast<void*>(&sinkhorn_kernel),
                             dim3(GBLK), dim3(TBLK), args, 0, stream);
}

// Round 7
// 126.882 us; speedup vs baseline: 1.0491x; 1.0491x over previous
//
#include <hip/hip_runtime.h>
#include <math.h>

#define EPS      0.1f
#define INV_EPS  10.0f
#define THRESH   0.1f
#define MAX_IT   20

// Problem sizes (fixed by reference setup_inputs)
#define BB 4
#define NN 1024
#define MM 1024
#define DD 512

#define MU_P (1.0f / 1024.0f + 1e-8f)

// Sinkhorn loop config: 128 blocks x 512 threads, 32 rows/block, 4 rows/wave
#define GBLK 128
#define TBLK 512

// workspace layout (float offsets)
#define OFF_K    ((size_t)0)                   // K = exp(-C/eps) [B,N,M] bf16 (8.4 MB)
#define OFF_XB   ((size_t)2097152)             // x in bf16 [B,N,D] (4.2 MB)
#define OFF_YB   ((size_t)3145728)             // y in bf16 [B,M,D] (4.2 MB)
#define OFF_NX   ((size_t)4194304)             // |x_i| [B*N]
#define OFF_NY   (OFF_NX + 4096)               // |y_j| [B*M]
#define OFF_NUP  (OFF_NY + 4096)               // nu + 1e-8 [B*M]
#define OFF_CS   (OFF_NUP + 4096)              // colsum rotation [3][4096]
#define OFF_FLG  (OFF_CS + 12288)              // barrier flags [2][128] ulong

#define GLDA 40  // padded ushort row stride (80 B): bank-balanced, 16B-aligned rows

typedef __bf16 bf16x8 __attribute__((ext_vector_type(8)));
typedef float f32x4 __attribute__((ext_vector_type(4)));
typedef unsigned long long u64;

__device__ __forceinline__ float wave_reduce_sum(float x) {
#pragma unroll
  for (int off = 32; off > 0; off >>= 1) x += __shfl_xor(x, off, 64);
  return x;
}

// pack two floats to bf16x2 (RNE via compiler cast)
__device__ __forceinline__ uint pk2(float a, float b) {
  __bf16 ha = (__bf16)a, hb = (__bf16)b;
  return (uint)*(ushort*)&ha | ((uint)*(ushort*)&hb << 16);
}

// -------- prep: fp32 norms of x/y rows (from ORIGINAL fp32), x/y -> bf16,
// sinkhorn state init (merged). One wave per 512-float row. --------
__global__ void __launch_bounds__(256) prep_kernel(const float* __restrict__ x,
                                                   const float* __restrict__ y,
                                                   ushort* __restrict__ xb,
                                                   ushort* __restrict__ yb,
                                                   float* __restrict__ nx,
                                                   float* __restrict__ ny,
                                                   const float* __restrict__ nu,
                                                   float* nup, float* colsum,
                                                   int* flagsi, float* out) {
  const int tid = threadIdx.x;
  int gt = blockIdx.x * 256 + tid;
  if (gt < BB * MM) {
    nup[gt] = nu[gt] + 1e-8f;
    colsum[4096 + gt] = 0.f;      // colsum[1] is iteration 0's add target
  }
  if (gt < 512) flagsi[gt] = 0;   // 2 x 128 ulong flag slots
  if (gt < BB) out[gt] = 0.f;

  const int w = tid >> 6, lane = tid & 63;
  const int r = blockIdx.x * 4 + w;                 // 0..8191
  const bool isx = (r < BB * NN);
  const float* src = isx ? (x + (size_t)r * DD)
                         : (y + (size_t)(r - BB * NN) * DD);
  ushort* dst = isx ? (xb + (size_t)r * DD)
                    : (yb + (size_t)(r - BB * NN) * DD);
  const float4* s4 = (const float4*)src;
  float4 a = s4[lane * 2];          // 8 contiguous floats per lane
  float4 b = s4[lane * 2 + 1];
  float ss = a.x * a.x + a.y * a.y + a.z * a.z + a.w * a.w +
             b.x * b.x + b.y * b.y + b.z * b.z + b.w * b.w;
  uint4 pk = make_uint4(pk2(a.x, a.y), pk2(a.z, a.w), pk2(b.x, b.y), pk2(b.z, b.w));
  *(uint4*)(dst + lane * 8) = pk;
  ss = wave_reduce_sum(ss);
  if (lane == 0) {
    float n = sqrtf(ss);
    if (isx) nx[r] = n; else ny[r - BB * NN] = n;
  }
}

// -------- MFMA bf16 GEMM (bf16-staged): dot = X Y^T, 128x128 tile, 256 thr,
// 4 waves of 4x4 16x16x32 frags; epilogue K = exp(-(1-dot/den)/eps), bf16. --------
__global__ void __launch_bounds__(256) gemm_kernel(const ushort* __restrict__ xb,
                                                   const ushort* __restrict__ yb,
                                                   const float* __restrict__ nxg,
                                                   const float* __restrict__ nyg,
                                                   ushort* __restrict__ K) {
  __shared__ ushort Ah[128 * GLDA];    // 10.2 KB
  __shared__ ushort Bh[128 * GLDA];    // 10.2 KB
  __shared__ float s_nx[128], s_ny[128];

  const int b = blockIdx.z;
  const int i0 = blockIdx.y * 128;   // m-tile
  const int j0 = blockIdx.x * 128;   // n-tile
  const int t = threadIdx.x;
  const int w = t >> 6, lane = t & 63;
  const int m16 = lane & 15, q = lane >> 4;
  const int wm = (w & 1) * 64, wn = (w >> 1) * 64;

  const int srow = t >> 1;             // 0..127 staging row
  const int soff = (t & 1) * 16;       // halves offset within 32-half row chunk

  const ushort* xrow = xb + ((size_t)b * NN + i0 + srow) * DD + soff;
  const ushort* yrow = yb + ((size_t)b * MM + j0 + srow) * DD + soff;

  f32x4 acc[4][4];
#pragma unroll
  for (int mi = 0; mi < 4; ++mi)
#pragma unroll
    for (int ni = 0; ni < 4; ++ni) acc[mi][ni] = (f32x4)0.f;

  for (int k0 = 0; k0 < DD; k0 += 32) {
    uint4 av0 = *(const uint4*)(xrow + k0);
    uint4 av1 = *(const uint4*)(xrow + k0 + 8);
    uint4 bv0 = *(const uint4*)(yrow + k0);
    uint4 bv1 = *(const uint4*)(yrow + k0 + 8);
    __syncthreads();
    *(uint4*)&Ah[srow * GLDA + soff] = av0;
    *(uint4*)&Ah[srow * GLDA + soff + 8] = av1;
    *(uint4*)&Bh[srow * GLDA + soff] = bv0;
    *(uint4*)&Bh[srow * GLDA + soff + 8] = bv1;
    __syncthreads();

    bf16x8 ahf[4], bhf[4];
#pragma unroll
    for (int mi = 0; mi < 4; ++mi)
      ahf[mi] = *(const bf16x8*)&Ah[(wm + mi * 16 + m16) * GLDA + q * 8];
#pragma unroll
    for (int ni = 0; ni < 4; ++ni)
      bhf[ni] = *(const bf16x8*)&Bh[(wn + ni * 16 + m16) * GLDA + q * 8];
#pragma unroll
    for (int mi = 0; mi < 4; ++mi)
#pragma unroll
      for (int ni = 0; ni < 4; ++ni)
        acc[mi][ni] = __builtin_amdgcn_mfma_f32_16x16x32_bf16(ahf[mi], bhf[ni], acc[mi][ni], 0, 0, 0);
  }

  // epilogue: K = exp(-(1 - dot/den)/eps), bf16
  if (t < 128) s_nx[t] = nxg[b * NN + i0 + t];
  else s_ny[t - 128] = nyg[b * MM + j0 + t - 128];
  __syncthreads();

#pragma unroll
  for (int mi = 0; mi < 4; ++mi)
#pragma unroll
    for (int ni = 0; ni < 4; ++ni)
#pragma unroll
      for (int r = 0; r < 4; ++r) {
        const int m = wm + mi * 16 + q * 4 + r;
        const int n = wn + ni * 16 + m16;
        float den = fmaxf(s_nx[m] * s_ny[n], 1e-8f);
        float cv = 1.0f - acc[mi][ni][r] / den;
        float kf = __expf(-cv * INV_EPS);
        __bf16 hb = (__bf16)kf;
        K[((size_t)b * NN + i0 + m) * MM + j0 + n] = *(ushort*)&hb;
      }
}

__device__ __forceinline__ void unpack8(uint4 k, float* kf) {
  kf[0] = __uint_as_float(k.x << 16);
  kf[1] = __uint_as_float(k.x & 0xffff0000u);
  kf[2] = __uint_as_float(k.y << 16);
  kf[3] = __uint_as_float(k.y & 0xffff0000u);
  kf[4] = __uint_as_float(k.z << 16);
  kf[5] = __uint_as_float(k.z & 0xffff0000u);
  kf[6] = __uint_as_float(k.w << 16);
  kf[7] = __uint_as_float(k.w & 0xffff0000u);
}

// -------- persistent Sinkhorn, ONE barrier per iteration (round-5 config) --------
// rowsum_i = sum_j K_ij wv_j ; u_i = eps(log mu' - log rowsum_i); wu_i = mu'/rowsum_i
// colsum_j = sum_i K_ij wu_i (atomic-accumulated grid-wide, 3-buffer rotation)
// wv_j = nu'_j / colsum_j (recomputed LOCALLY by every block -> no v-barrier)
// barrier: all-to-all, one ulong {gen, err} per block, depth-2 ping-pong slots.
__global__ void __launch_bounds__(TBLK) sinkhorn_kernel(
    const ushort* __restrict__ K, float* __restrict__ colsum,
    const float* __restrict__ nup, u64* __restrict__ flags,
    float* __restrict__ out) {
  const int tid = threadIdx.x;
  const int bid = blockIdx.x;
  const int lane = tid & 63;
  const int w = tid >> 6;                 // 0..7
  const int b = bid >> 5;                 // batch (32 blocks per batch)
  const int rbase = (bid & 31) * 32;      // first owned row within batch

  __shared__ float swv[1024];
  __shared__ float spart[8][1024];        // 32 KB per-wave column partials
  __shared__ float s_red;
  __shared__ int s_conv;

  const float eps_log_mu = EPS * __logf(MU_P);
  float u_prev[4] = {0.f, 0.f, 0.f, 0.f};
  float wu_reg[4] = {0.f, 0.f, 0.f, 0.f};
  int T = 0;

  for (int it = 0; it < MAX_IT; ++it) {
    const int genv = it + 1;
    // ---- stage wv (local v reconstruction; it=0: v=0 -> wv=1) ----
    if (tid == 0) s_red = 0.f;
    if (it == 0) {
      swv[tid] = 1.f;
      swv[tid + 512] = 1.f;
    } else {
      const float* cs = colsum + (it % 3) * 4096 + b * MM;
      float c0 = __hip_atomic_load(cs + tid, __ATOMIC_RELAXED, __HIP_MEMORY_SCOPE_AGENT);
      float c1 = __hip_atomic_load(cs + tid + 512, __ATOMIC_RELAXED, __HIP_MEMORY_SCOPE_AGENT);
      swv[tid] = nup[b * MM + tid] / c0;
      swv[tid + 512] = nup[b * MM + tid + 512] / c1;
    }
    __syncthreads();

    float wvr[16];
    {
      const float4* wp = (const float4*)swv;
      *(float4*)&wvr[0] = wp[lane * 2];
      *(float4*)&wvr[4] = wp[lane * 2 + 1];
      *(float4*)&wvr[8] = wp[128 + lane * 2];
      *(float4*)&wvr[12] = wp[129 + lane * 2];
    }
    float creg[16];
#pragma unroll
    for (int t2 = 0; t2 < 16; ++t2) creg[t2] = 0.f;

    // preload this wave's 4 K-rows (L2-resident)
    uint4 kq[4][2];
#pragma unroll
    for (int rr = 0; rr < 4; ++rr) {
      const uint4* kp = (const uint4*)(K + ((size_t)b * NN + rbase + w * 4 + rr) * MM);
      kq[rr][0] = kp[lane];
      kq[rr][1] = kp[lane + 64];
    }

    float werr = 0.f;
#pragma unroll
    for (int rr = 0; rr < 4; ++rr) {
      float kf[16];
      unpack8(kq[rr][0], kf);
      unpack8(kq[rr][1], kf + 8);
      float s = 0.f;
#pragma unroll
      for (int t2 = 0; t2 < 16; ++t2) s = fmaf(kf[t2], wvr[t2], s);
      s = wave_reduce_sum(s);
      float unv = eps_log_mu - EPS * __logf(s);
      werr += fabsf(unv - u_prev[rr]);
      u_prev[rr] = unv;
      float wu = MU_P / s;          // exp(u_new/eps), exactly
      wu_reg[rr] = wu;
#pragma unroll
      for (int t2 = 0; t2 < 16; ++t2) creg[t2] = fmaf(wu, kf[t2], creg[t2]);
    }
    if (lane == 0) atomicAdd(&s_red, werr);

    // publish per-wave column partials to LDS
    {
      float* pr = &spart[w][0];
      *(float4*)&pr[lane * 8] = *(float4*)&creg[0];
      *(float4*)&pr[lane * 8 + 4] = *(float4*)&creg[4];
      *(float4*)&pr[512 + lane * 8] = *(float4*)&creg[8];
      *(float4*)&pr[512 + lane * 8 + 4] = *(float4*)&creg[12];
    }
    __syncthreads();

    // cross-wave reduce + atomic add into next colsum; zero rotation buffer
    {
      float* csn = colsum + ((it + 1) % 3) * 4096 + b * MM;
      const int j0 = tid * 2;
      float s0 = 0.f, s1 = 0.f;
#pragma unroll
      for (int ww = 0; ww < 8; ++ww) {
        float2 p = *(const float2*)&spart[ww][j0];
        s0 += p.x;
        s1 += p.y;
      }
      unsafeAtomicAdd(&csn[j0], s0);
      unsafeAtomicAdd(&csn[j0 + 1], s1);
      if (tid < 32) {
        float* csz = colsum + ((it + 2) % 3) * 4096;
        __hip_atomic_store(&csz[bid * 32 + tid], 0.f, __ATOMIC_RELAXED, __HIP_MEMORY_SCOPE_AGENT);
      }
    }

    // ---- all-to-all barrier: publish {gen, err}, poll, local conv decision ----
    asm volatile("s_waitcnt vmcnt(0)" ::: "memory");
    __syncthreads();
    if (tid == 0) {
      u64 f = ((u64)(uint)genv << 32) | (u64)__float_as_uint(s_red);
      __hip_atomic_store(&flags[(genv & 1) * GBLK + bid], f, __ATOMIC_RELAXED, __HIP_MEMORY_SCOPE_AGENT);
    }
    if (tid < 64) {
      const u64* fl = flags + (genv & 1) * GBLK;
      u64 f0, f1;
      for (;;) {
        f0 = __hip_atomic_load(fl + tid, __ATOMIC_RELAXED, __HIP_MEMORY_SCOPE_AGENT);
        f1 = __hip_atomic_load(fl + tid + 64, __ATOMIC_RELAXED, __HIP_MEMORY_SCOPE_AGENT);
        if (__all(((f0 >> 32) >= (u64)genv) && ((f1 >> 32) >= (u64)genv))) break;
        __builtin_amdgcn_s_sleep(1);
      }
      float e = __uint_as_float((uint)f0) + __uint_as_float((uint)f1);
      e = wave_reduce_sum(e);
      if (tid == 0) s_conv = (e * (1.0f / (float)BB) < THRESH) ? 1 : 0;
    }
    __syncthreads();
    T = it;
    if (s_conv) break;
  }

  // ---- final: reconstruct converged wv locally, accumulate transport cost ----
  {
    const float* cs = colsum + ((T + 1) % 3) * 4096 + b * MM;
    float c0 = __hip_atomic_load(cs + tid, __ATOMIC_RELAXED, __HIP_MEMORY_SCOPE_AGENT);
    float c1 = __hip_atomic_load(cs + tid + 512, __ATOMIC_RELAXED, __HIP_MEMORY_SCOPE_AGENT);
    swv[tid] = nup[b * MM + tid] / c0;
    swv[tid + 512] = nup[b * MM + tid + 512] / c1;
  }
  if (tid == 0) s_red = 0.f;
  __syncthreads();

  float wvr[16];
  {
    const float4* wp = (const float4*)swv;
    *(float4*)&wvr[0] = wp[lane * 2];
    *(float4*)&wvr[4] = wp[lane * 2 + 1];
    *(float4*)&wvr[8] = wp[128 + lane * 2];
    *(float4*)&wvr[12] = wp[129 + lane * 2];
  }

  float wcost = 0.f;
#pragma unroll
  for (int rr = 0; rr < 4; ++rr) {
    const int r = rbase + w * 4 + rr;
    const uint4* kp = (const uint4*)(K + ((size_t)b * NN + r) * MM);
    uint4 k0 = kp[lane], k1 = kp[lane + 64];
    float kf[16];
    unpack8(k0, kf);
    unpack8(k1, kf + 8);
    float s = 0.f;
#pragma unroll
    for (int t2 = 0; t2 < 16; ++t2)
      s = fmaf(kf[t2] * wvr[t2], -EPS * __logf(kf[t2]), s);   // pi * C, C = -eps log K
    s = wave_reduce_sum(s) * wu_reg[rr];
    if (lane == 0) wcost += s;
  }
  if (lane == 0) atomicAdd(&s_red, wcost);
  __syncthreads();
  if (tid == 0) atomicAdd(out + b, s_red);
}

extern "C" void kernel_launch(void* const* d_in, const int* in_sizes, int n_in,
                              void* d_out, int out_size, void* d_ws, size_t ws_size,
                              hipStream_t stream) {
  const float* x = (const float*)d_in[0];
  const float* y = (const float*)d_in[1];
  const float* nu = (const float*)d_in[2];
  float* out = (float*)d_out;
  float* ws = (float*)d_ws;

  ushort* K = (ushort*)(ws + OFF_K);
  ushort* xb = (ushort*)(ws + OFF_XB);
  ushort* yb = (ushort*)(ws + OFF_YB);
  float* nx = ws + OFF_NX;
  float* ny = ws + OFF_NY;
  float* nup = ws + OFF_NUP;
  float* cs = ws + OFF_CS;
  u64* flg = (u64*)(ws + OFF_FLG);

  prep_kernel<<<2048, 256, 0, stream>>>(x, y, xb, yb, nx, ny, nu, nup, cs, (int*)flg, out);
  gemm_kernel<<<dim3(8, 8, 4), 256, 0, stream>>>(xb, yb, nx, ny, K);

  void* args[] = {(void*)&K, (void*)&cs, (void*)&nup, (void*)&flg, (void*)&out};
  hipLaunchCooperativeKernel(reinterpret_cast<void*>(&sinkhorn_kernel),
                             dim3(GBLK), dim3(TBLK), args, 0, stream);
}